// Round 5
// baseline (1063.562 us; speedup 1.0000x reference)
//
#include <hip/hip_runtime.h>
#include <hip/hip_bf16.h>

// ============================================================================
// EpisodeMultiheadAttentionBlock — round 5.
// f32 interface. bf16 MFMA internals. Changes vs r4:
//  * key_padding_mask dtype detection now handles bool-bytes / int32 / float32
//    (f32 0.0/1.0 previously misread as bool bytes -> mask dropped — prime
//    suspect for the persistent ~0.3 error).
//  * gate pre-activations Rb/Zb kept in f32 end-to-end (no bf16 double round).
//  * launch order: xr/xz gate GEMMs moved after attention; overlay layout
//    re-derived, peak 171,966,464 B (same as r3/r4).
// ============================================================================

typedef __attribute__((ext_vector_type(8))) short bf16x8;
typedef __attribute__((ext_vector_type(4))) float f32x4;

__device__ __forceinline__ short f2bs(float f) {
  union { __hip_bfloat16 h; short s; } u; u.h = __float2bfloat16(f); return u.s;
}

// ---------------- workspace layout (bytes); peak 171,966,464 ---------------
static constexpr size_t OFF_WT   = 0;            // 10 x 1M bf16 W^T (20,971,520)
static constexpr size_t OFF_XBF  = 20971520;     // bf16 x [16384][1024] (33,554,432)
static constexpr size_t OFF_QH   = 54525952;     // qh bf16 [b,h][512][64] (16,777,216)
static constexpr size_t OFF_KH   = 71303168;     // kh bf16 [b,h][1024][64] (33,554,432)
static constexpr size_t OFF_VT   = 104857600;    // vT bf16 [b,h][64][1024] (33,554,432)
// overlays (lifetimes vs launch order, all verified):
static constexpr size_t OFF_QLIN = 138412032;    // q f32 [8192][1024] pre-attn (33,554,432)
static constexpr size_t OFF_KLIN = 104857600;    // k f32 [16384][1024] pre-vt (67,108,864)
static constexpr size_t OFF_OAT  = 138412032;    // attn-out bf16 (16,777,216) post-qlin
static constexpr size_t OFF_O2   = 155189248;    // o2 bf16 (16,777,216) -> end 171,966,464
static constexpr size_t OFF_RB   = 54525952;     // Rb f32 (33,554,432) over dead qh+kh-head
static constexpr size_t OFF_ZB   = 88080384;     // Zb f32 (33,554,432) over dead kh-tail+vt-head
static constexpr size_t OFF_RX   = 121634816;    // rx bf16 (16,777,216) over dead vt-tail
static constexpr size_t OFF_HB   = 54525952;     // Hb f32 (33,554,432) over dead Rb

// ---------------- x: f32 -> bf16 ------------------------------------------
__global__ __launch_bounds__(256) void k_cvtx(const float* __restrict__ x,
                                              short* __restrict__ xbf) {
  size_t i = ((size_t)blockIdx.x * 256 + threadIdx.x) * 8;
  f32x4 a = *(const f32x4*)(x + i);
  f32x4 b = *(const f32x4*)(x + i + 4);
  bf16x8 o;
  o[0] = f2bs(a[0]); o[1] = f2bs(a[1]); o[2] = f2bs(a[2]); o[3] = f2bs(a[3]);
  o[4] = f2bs(b[0]); o[5] = f2bs(b[1]); o[6] = f2bs(b[2]); o[7] = f2bs(b[3]);
  *(bf16x8*)(xbf + i) = o;
}

// ---------------- weight transpose: W[k][n] f32 -> Wt[n][k] bf16 -----------
struct W10 { const float* p[10]; };
__global__ __launch_bounds__(256) void k_wt(W10 wsrc, short* __restrict__ wt) {
  __shared__ short t[32][33];
  int kb = blockIdx.x * 32, nb = blockIdx.y * 32, wi = blockIdx.z;
  const float* src = wsrc.p[wi];
  int tid = threadIdx.x;
#pragma unroll
  for (int e = 0; e < 4; ++e) {
    int idx = e * 256 + tid;
    int kr = idx >> 5, nc = idx & 31;
    t[nc][kr] = f2bs(src[(size_t)(kb + kr) * 1024 + nb + nc]);
  }
  __syncthreads();
  short* dst = wt + (size_t)wi * 1024 * 1024;
#pragma unroll
  for (int e = 0; e < 4; ++e) {
    int idx = e * 256 + tid;
    int nr = idx >> 5, kc = idx & 31;
    dst[(size_t)(nb + nr) * 1024 + kb + kc] = t[nr][kc];
  }
}

// ---------------- standalone RoPE + head-scatter (f64 trig) ----------------
__global__ __launch_bounds__(256) void k_rope(const float* __restrict__ lin,
                                              __hip_bfloat16* __restrict__ outp,
                                              const int* __restrict__ kidx,
                                              int sh, int qoff) {
  int gid = blockIdx.x * 256 + threadIdx.x;
  int row = gid >> 9, j = gid & 511;
  int b = row >> sh, s = row & ((1 << sh) - 1);
  int idx = kidx[b * 1024 + qoff + s];
  float2 v = ((const float2*)lin)[(size_t)row * 512 + j];
  double inv = pow(10000.0, -(double)j / 512.0);
  double ds, dc;
  sincos((double)idx * inv, &ds, &dc);
  float c = (float)dc, sn = (float)ds;
  float e0 = v.x * c - v.y * sn;
  float e1 = v.x * sn + v.y * c;
  int h = j >> 5, d0 = (2 * j) & 63;
  size_t o = ((size_t)(b * 16 + h) * ((size_t)1 << sh) + s) * 64 + d0;
  unsigned u = ((unsigned)(unsigned short)f2bs(e1) << 16) |
               (unsigned)(unsigned short)f2bs(e0);
  *(unsigned*)((short*)outp + o) = u;
}

// ---------------- generic 128x128 MFMA GEMM (m97 structure) ----------------
enum { CM_BF16 = 0, CM_F32 = 2, CM_F32ACC = 3, CM_VT = 4 };

__global__ __launch_bounds__(256) void k_gemm(
    const short* __restrict__ A, const short* __restrict__ Bt,
    const float* __restrict__ bias, int amode, int cmode,
    void* __restrict__ Cout) {
  __shared__ __align__(16) short lA[128 * 32];
  __shared__ __align__(16) short lB[128 * 32];
  const int tid = threadIdx.x;
  const int lane = tid & 63;
  const int wv = tid >> 6;
  const int wm = wv >> 1, wn = wv & 1;
  const int lo = lane & 15, hi = lane >> 4;
  const int tm0 = blockIdx.x * 128;
  const int tn0 = blockIdx.y * 128;

  const f32x4 vz = {0.f, 0.f, 0.f, 0.f};
  f32x4 acc[4][4];
#pragma unroll
  for (int m = 0; m < 4; ++m)
#pragma unroll
    for (int n = 0; n < 4; ++n) acc[m][n] = vz;

  for (int kt = 0; kt < 32; ++kt) {
    const int k0 = kt * 32;
    __syncthreads();
#pragma unroll
    for (int i = 0; i < 2; ++i) {
      int f = i * 256 + tid;
      int r = f >> 2;
      int cb = (f & 3) * 16;
      int arow = tm0 + r;
      if (amode) arow = ((arow >> 9) << 10) + 512 + (arow & 511);
      const char* ga = (const char*)(A + (size_t)arow * 1024 + k0) + cb;
      __builtin_amdgcn_global_load_lds(
          (const __attribute__((address_space(1))) void*)ga,
          (__attribute__((address_space(3))) void*)((char*)lA + (size_t)(i * 256 + wv * 64) * 16),
          16, 0, 0);
      int brow = tn0 + r;
      const char* gb = (const char*)(Bt + (size_t)brow * 1024 + k0) + cb;
      __builtin_amdgcn_global_load_lds(
          (const __attribute__((address_space(1))) void*)gb,
          (__attribute__((address_space(3))) void*)((char*)lB + (size_t)(i * 256 + wv * 64) * 16),
          16, 0, 0);
    }
    __syncthreads();
    bf16x8 af[4], bfr[4];
#pragma unroll
    for (int m = 0; m < 4; ++m)
      af[m] = *(const bf16x8*)&lA[(wm * 64 + m * 16 + lo) * 32 + hi * 8];
#pragma unroll
    for (int n = 0; n < 4; ++n)
      bfr[n] = *(const bf16x8*)&lB[(wn * 64 + n * 16 + lo) * 32 + hi * 8];
#pragma unroll
    for (int m = 0; m < 4; ++m)
#pragma unroll
      for (int n = 0; n < 4; ++n)
        acc[m][n] = __builtin_amdgcn_mfma_f32_16x16x32_bf16(af[m], bfr[n], acc[m][n], 0, 0, 0);
  }

  if (cmode == CM_VT) {
    __hip_bfloat16* out = (__hip_bfloat16*)Cout;
#pragma unroll
    for (int m = 0; m < 4; ++m) {
      int row_base = tm0 + wm * 64 + m * 16 + hi * 4;
#pragma unroll
      for (int n = 0; n < 4; ++n) {
        int col = tn0 + wn * 64 + n * 16 + lo;
        float bsv = bias ? bias[col] : 0.f;
        int hh = col >> 6, dd = col & 63;
#pragma unroll
        for (int r = 0; r < 4; ++r) {
          int row = row_base + r;
          int bb = row >> 10, ss = row & 1023;
          out[((size_t)(bb * 16 + hh) * 64 + dd) * 1024 + ss] =
              __float2bfloat16(acc[m][n][r] + bsv);
        }
      }
    }
  } else if (cmode == CM_F32 || cmode == CM_F32ACC) {
    float* out = (float*)Cout;
#pragma unroll
    for (int m = 0; m < 4; ++m) {
      int row_base = tm0 + wm * 64 + m * 16 + hi * 4;
#pragma unroll
      for (int n = 0; n < 4; ++n) {
        int col = tn0 + wn * 64 + n * 16 + lo;
        float bsv = bias ? bias[col] : 0.f;
#pragma unroll
        for (int r = 0; r < 4; ++r) {
          size_t off = (size_t)(row_base + r) * 1024 + col;
          float val = acc[m][n][r] + bsv;
          if (cmode == CM_F32ACC) val += out[off];
          out[off] = val;
        }
      }
    }
  } else {
    __hip_bfloat16* out = (__hip_bfloat16*)Cout;
#pragma unroll
    for (int m = 0; m < 4; ++m) {
      int row_base = tm0 + wm * 64 + m * 16 + hi * 4;
#pragma unroll
      for (int n = 0; n < 4; ++n) {
        int col = tn0 + wn * 64 + n * 16 + lo;
        float bsv = bias ? bias[col] : 0.f;
#pragma unroll
        for (int r = 0; r < 4; ++r) {
          size_t off = (size_t)(row_base + r) * 1024 + col;
          out[off] = __float2bfloat16(acc[m][n][r] + bsv);
        }
      }
    }
  }
}

// ---------------- attention (QBLK=16, static 64KB LDS) ---------------------
__global__ __launch_bounds__(256) void k_attn(
    const __hip_bfloat16* __restrict__ qh,
    const __hip_bfloat16* __restrict__ kh,
    const __hip_bfloat16* __restrict__ vt,
    const unsigned char* __restrict__ padraw,
    float* __restrict__ mean_out,
    __hip_bfloat16* __restrict__ oat) {
  __shared__ float Sld[16 * 1024];
  const int qt = blockIdx.x, h = blockIdx.y, b = blockIdx.z;
  const int tid = threadIdx.x, lane = tid & 63, wv = tid >> 6;
  const int lo = lane & 15, hi = lane >> 4;
  const __hip_bfloat16* qbh = qh + (size_t)(b * 16 + h) * 512 * 64 + (size_t)qt * 16 * 64;
  const __hip_bfloat16* kbh = kh + (size_t)(b * 16 + h) * 1024 * 64;
  const __hip_bfloat16* vbh = vt + (size_t)(b * 16 + h) * 64 * 1024;
  const f32x4 vz = {0.f, 0.f, 0.f, 0.f};

  // --- pad-mask element-width detect (bool bytes vs int32 vs float32) ---
  // 1-byte bool data: random 0x01 bytes appear at non-word-aligned offsets.
  // int32 0/1: bytes at off%4!=0 are always 0x00.  f32 0.0f/1.0f: bytes are
  // only {0x00,0x80,0x3F}.  So "0x01 at off%4!=0" <=> 1-byte data.
  bool is_byte = false;
#pragma unroll
  for (int j = 1; j < 256; ++j)
    if ((j & 3) && padraw[j] == 1) is_byte = true;
  const int* ipad = (const int*)padraw;

  bf16x8 qf0 = *(const bf16x8*)(qbh + (size_t)lo * 64 + hi * 8);
  bf16x8 qf1 = *(const bf16x8*)(qbh + (size_t)lo * 64 + 32 + hi * 8);

  for (int nt = 0; nt < 16; ++nt) {
    int kp0 = wv * 256 + nt * 16;
    bf16x8 kf0 = *(const bf16x8*)(kbh + (size_t)(kp0 + lo) * 64 + hi * 8);
    bf16x8 kf1 = *(const bf16x8*)(kbh + (size_t)(kp0 + lo) * 64 + 32 + hi * 8);
    f32x4 sa = vz;
    sa = __builtin_amdgcn_mfma_f32_16x16x32_bf16(qf0, kf0, sa, 0, 0, 0);
    sa = __builtin_amdgcn_mfma_f32_16x16x32_bf16(qf1, kf1, sa, 0, 0, 0);
    int kpos = kp0 + lo;
    // nonzero word covers both int32 0/1 and f32 0.0f/1.0f bit patterns
    int pk = is_byte ? (int)padraw[b * 1024 + kpos]
                     : (ipad[b * 1024 + kpos] != 0 ? 1 : 0);
#pragma unroll
    for (int r = 0; r < 4; ++r) {
      int q = hi * 4 + r;
      int qg = 512 + qt * 16 + q;
      float sv = sa[r] * 0.125f;
      bool msk = (kpos > qg) || (kpos < qg && pk != 0);
      Sld[q * 1024 + kpos] = msk ? -1e30f : sv;
    }
  }
  __syncthreads();

  for (int rr = 0; rr < 4; ++rr) {
    int q = wv * 4 + rr;
    float* row = Sld + q * 1024;
    float v[16], mx = -1e30f;
#pragma unroll
    for (int i = 0; i < 16; ++i) { v[i] = row[lane + i * 64]; mx = fmaxf(mx, v[i]); }
#pragma unroll
    for (int off = 32; off > 0; off >>= 1) mx = fmaxf(mx, __shfl_xor(mx, off));
    float sum = 0.f;
#pragma unroll
    for (int i = 0; i < 16; ++i) { v[i] = __expf(v[i] - mx); sum += v[i]; }
#pragma unroll
    for (int off = 32; off > 0; off >>= 1) sum += __shfl_xor(sum, off);
    float invs = 1.0f / sum;
    size_t mrow = ((size_t)b * 512 + qt * 16 + q) * 1024;
#pragma unroll
    for (int i = 0; i < 16; ++i) {
      float p = v[i] * invs;
      row[lane + i * 64] = p;
      atomicAdd(mean_out + mrow + lane + i * 64, p * 0.0625f);
    }
  }
  __syncthreads();

  f32x4 oacc = vz;
  for (int kc = 0; kc < 32; ++kc) {
    bf16x8 vf = *(const bf16x8*)(vbh + (size_t)(wv * 16 + lo) * 1024 + kc * 32 + hi * 8);
    const float* prow = Sld + lo * 1024 + kc * 32 + hi * 8;
    f32x4 p0 = *(const f32x4*)prow;
    f32x4 p1 = *(const f32x4*)(prow + 4);
    bf16x8 pa;
    pa[0] = f2bs(p0[0]); pa[1] = f2bs(p0[1]); pa[2] = f2bs(p0[2]); pa[3] = f2bs(p0[3]);
    pa[4] = f2bs(p1[0]); pa[5] = f2bs(p1[1]); pa[6] = f2bs(p1[2]); pa[7] = f2bs(p1[3]);
    oacc = __builtin_amdgcn_mfma_f32_16x16x32_bf16(pa, vf, oacc, 0, 0, 0);
  }
#pragma unroll
  for (int r = 0; r < 4; ++r) {
    int q = qt * 16 + hi * 4 + r;
    oat[((size_t)b * 512 + q) * 1024 + h * 64 + wv * 16 + lo] = __float2bfloat16(oacc[r]);
  }
}

// ---------------- gate elementwise kernels (f32 pre-activations) -----------
__global__ __launch_bounds__(256) void k_rx(const float* __restrict__ Rb,
                                            const float* __restrict__ x,
                                            short* __restrict__ rx) {
  size_t base = ((size_t)blockIdx.x * 256 + threadIdx.x) * 4;
  int row = (int)(base >> 10), col = (int)(base & 1023);
  int b = row >> 9, s = row & 511;
  const float* xp = x + ((size_t)(b * 1024 + 512 + s) << 10) + col;
  f32x4 rv = *(const f32x4*)(Rb + base);
  f32x4 xv = *(const f32x4*)xp;
  typedef __attribute__((ext_vector_type(4))) short s16x4;
  s16x4 o;
#pragma unroll
  for (int j = 0; j < 4; ++j) {
    float r = 1.f / (1.f + __expf(-rv[j]));
    o[j] = f2bs(r * xv[j]);
  }
  *(s16x4*)(rx + base) = o;
}

__global__ __launch_bounds__(256) void k_final(const float* __restrict__ Zb,
                                               const float* __restrict__ Hb,
                                               const float* __restrict__ x,
                                               float* __restrict__ out0) {
  size_t base = ((size_t)blockIdx.x * 256 + threadIdx.x) * 4;
  int row = (int)(base >> 10), col = (int)(base & 1023);
  int b = row >> 9, s = row & 511;
  const float* xp = x + ((size_t)(b * 1024 + 512 + s) << 10) + col;
  f32x4 zv = *(const f32x4*)(Zb + base);
  f32x4 hv = *(const f32x4*)(Hb + base);
  f32x4 xv = *(const f32x4*)xp;
  f32x4 o;
#pragma unroll
  for (int j = 0; j < 4; ++j) {
    float z = 1.f / (1.f + __expf(-zv[j]));
    float hh = tanhf(hv[j]);
    o[j] = (1.f - z) * xv[j] + z * hh;
  }
  *(f32x4*)(out0 + base) = o;
}

// ============================================================================
extern "C" void kernel_launch(void* const* d_in, const int* in_sizes, int n_in,
                              void* d_out, int out_size, void* d_ws, size_t ws_size,
                              hipStream_t stream) {
  const float* key_in = (const float*)d_in[0];
  const int* key_index = (const int*)d_in[1];
  const unsigned char* pad = (const unsigned char*)d_in[2];
  const float* W[10] = {(const float*)d_in[3],  (const float*)d_in[5],
                        (const float*)d_in[7],  (const float*)d_in[9],
                        (const float*)d_in[11], (const float*)d_in[13],
                        (const float*)d_in[15], (const float*)d_in[17],
                        (const float*)d_in[19], (const float*)d_in[21]};
  const float* bq  = (const float*)d_in[4];
  const float* bk  = (const float*)d_in[6];
  const float* bv  = (const float*)d_in[8];
  const float* bo  = (const float*)d_in[10];
  const float* bxr = (const float*)d_in[12];
  const float* byr = (const float*)d_in[14];
  const float* bxz = (const float*)d_in[16];
  const float* byz = (const float*)d_in[18];
  const float* bxg = (const float*)d_in[20];
  const float* byg = (const float*)d_in[22];

  char* ws = (char*)d_ws;
  short* wt = (short*)(ws + OFF_WT);
  short* xbf = (short*)(ws + OFF_XBF);
  __hip_bfloat16* qh = (__hip_bfloat16*)(ws + OFF_QH);
  __hip_bfloat16* kh = (__hip_bfloat16*)(ws + OFF_KH);
  __hip_bfloat16* vt = (__hip_bfloat16*)(ws + OFF_VT);
  float* qlin = (float*)(ws + OFF_QLIN);
  float* klin = (float*)(ws + OFF_KLIN);
  float* Rb = (float*)(ws + OFF_RB);
  float* Zb = (float*)(ws + OFF_ZB);
  __hip_bfloat16* oat = (__hip_bfloat16*)(ws + OFF_OAT);
  short* o2 = (short*)(ws + OFF_O2);
  short* rx = (short*)(ws + OFF_RX);
  float* Hb = (float*)(ws + OFF_HB);

  float* out0 = (float*)d_out;
  float* out1 = out0 + (size_t)8388608;

  // out1 accumulated via atomics -> zero every call (replay-safe).
  hipMemsetAsync(out1, 0, (size_t)33554432, stream);

  W10 wargs;
  for (int i = 0; i < 10; ++i) wargs.p[i] = W[i];
  k_cvtx<<<8192, 256, 0, stream>>>(key_in, xbf);
  k_wt<<<dim3(32, 32, 10), 256, 0, stream>>>(wargs, wt);

  // q/k/v projections (+rope, +fused V-transpose)
  k_gemm<<<dim3(64, 8), 256, 0, stream>>>(xbf, wt + (size_t)0 * 1048576, bq, 1, CM_F32,
                                          (void*)qlin);
  k_rope<<<16384, 256, 0, stream>>>(qlin, qh, key_index, 9, 512);
  k_gemm<<<dim3(128, 8), 256, 0, stream>>>(xbf, wt + (size_t)1 * 1048576, bk, 0, CM_F32,
                                           (void*)klin);
  k_rope<<<32768, 256, 0, stream>>>(klin, kh, key_index, 10, 0);
  k_gemm<<<dim3(128, 8), 256, 0, stream>>>(xbf, wt + (size_t)2 * 1048576, bv, 0, CM_VT,
                                           (void*)vt);

  // attention (oat -> dead-qlin region; mean -> d_out directly)
  k_attn<<<dim3(32, 16, 16), 256, 0, stream>>>(qh, kh, vt, pad, out1, oat);

  // output projection + gates (qh/kh/vt dead from here; overlays kick in)
  k_gemm<<<dim3(64, 8), 256, 0, stream>>>((const short*)oat, wt + (size_t)3 * 1048576, bo,
                                          0, CM_BF16, (void*)o2);
  k_gemm<<<dim3(64, 8), 256, 0, stream>>>(xbf, wt + (size_t)4 * 1048576, bxr, 1, CM_F32,
                                          (void*)Rb);
  k_gemm<<<dim3(64, 8), 256, 0, stream>>>(o2, wt + (size_t)5 * 1048576, byr, 0, CM_F32ACC,
                                          (void*)Rb);
  k_gemm<<<dim3(64, 8), 256, 0, stream>>>(xbf, wt + (size_t)6 * 1048576, bxz, 1, CM_F32,
                                          (void*)Zb);
  k_gemm<<<dim3(64, 8), 256, 0, stream>>>(o2, wt + (size_t)7 * 1048576, byz, 0, CM_F32ACC,
                                          (void*)Zb);
  k_rx<<<8192, 256, 0, stream>>>(Rb, key_in, rx);
  k_gemm<<<dim3(64, 8), 256, 0, stream>>>(rx, wt + (size_t)8 * 1048576, bxg, 0, CM_F32,
                                          (void*)Hb);
  k_gemm<<<dim3(64, 8), 256, 0, stream>>>(o2, wt + (size_t)9 * 1048576, byg, 0, CM_F32ACC,
                                          (void*)Hb);
  k_final<<<8192, 256, 0, stream>>>(Zb, Hb, key_in, out0);
}

// Round 6
// 963.738 us; speedup vs baseline: 1.1036x; 1.1036x over previous
//
#include <hip/hip_runtime.h>
#include <hip/hip_bf16.h>

// ============================================================================
// EpisodeMultiheadAttentionBlock — round 6.
// r5 passed (absmax 0.031). This round: k_attn rewrite only.
//  * head-loop inside block; mean accumulated in registers -> no atomics,
//    no out1 memset (was 540MB of L2 atomic traffic).
//  * LDS XOR swizzle f(q,k)=k^q; PV reads as 8x ds_read_b32 -> conflict-free
//    (was 16-way at stride 1024).
//  * K/V register prefetch; pad mask hoisted to a 16-bit register mask.
// GEMM path byte-identical to r5.
// ============================================================================

typedef __attribute__((ext_vector_type(8))) short bf16x8;
typedef __attribute__((ext_vector_type(4))) float f32x4;

__device__ __forceinline__ short f2bs(float f) {
  union { __hip_bfloat16 h; short s; } u; u.h = __float2bfloat16(f); return u.s;
}

// ---------------- workspace layout (bytes); peak 171,966,464 ---------------
static constexpr size_t OFF_WT   = 0;            // 10 x 1M bf16 W^T (20,971,520)
static constexpr size_t OFF_XBF  = 20971520;     // bf16 x [16384][1024] (33,554,432)
static constexpr size_t OFF_QH   = 54525952;     // qh bf16 [b,h][512][64] (16,777,216)
static constexpr size_t OFF_KH   = 71303168;     // kh bf16 [b,h][1024][64] (33,554,432)
static constexpr size_t OFF_VT   = 104857600;    // vT bf16 [b,h][64][1024] (33,554,432)
// overlays (lifetimes vs launch order, all verified):
static constexpr size_t OFF_QLIN = 138412032;    // q f32 [8192][1024] pre-attn (33,554,432)
static constexpr size_t OFF_KLIN = 104857600;    // k f32 [16384][1024] pre-vt (67,108,864)
static constexpr size_t OFF_OAT  = 138412032;    // attn-out bf16 (16,777,216) post-qlin
static constexpr size_t OFF_O2   = 155189248;    // o2 bf16 (16,777,216) -> end 171,966,464
static constexpr size_t OFF_RB   = 54525952;     // Rb f32 (33,554,432) over dead qh+kh-head
static constexpr size_t OFF_ZB   = 88080384;     // Zb f32 (33,554,432) over dead kh-tail+vt-head
static constexpr size_t OFF_RX   = 121634816;    // rx bf16 (16,777,216) over dead vt-tail
static constexpr size_t OFF_HB   = 54525952;     // Hb f32 (33,554,432) over dead Rb

// ---------------- x: f32 -> bf16 ------------------------------------------
__global__ __launch_bounds__(256) void k_cvtx(const float* __restrict__ x,
                                              short* __restrict__ xbf) {
  size_t i = ((size_t)blockIdx.x * 256 + threadIdx.x) * 8;
  f32x4 a = *(const f32x4*)(x + i);
  f32x4 b = *(const f32x4*)(x + i + 4);
  bf16x8 o;
  o[0] = f2bs(a[0]); o[1] = f2bs(a[1]); o[2] = f2bs(a[2]); o[3] = f2bs(a[3]);
  o[4] = f2bs(b[0]); o[5] = f2bs(b[1]); o[6] = f2bs(b[2]); o[7] = f2bs(b[3]);
  *(bf16x8*)(xbf + i) = o;
}

// ---------------- weight transpose: W[k][n] f32 -> Wt[n][k] bf16 -----------
struct W10 { const float* p[10]; };
__global__ __launch_bounds__(256) void k_wt(W10 wsrc, short* __restrict__ wt) {
  __shared__ short t[32][33];
  int kb = blockIdx.x * 32, nb = blockIdx.y * 32, wi = blockIdx.z;
  const float* src = wsrc.p[wi];
  int tid = threadIdx.x;
#pragma unroll
  for (int e = 0; e < 4; ++e) {
    int idx = e * 256 + tid;
    int kr = idx >> 5, nc = idx & 31;
    t[nc][kr] = f2bs(src[(size_t)(kb + kr) * 1024 + nb + nc]);
  }
  __syncthreads();
  short* dst = wt + (size_t)wi * 1024 * 1024;
#pragma unroll
  for (int e = 0; e < 4; ++e) {
    int idx = e * 256 + tid;
    int nr = idx >> 5, kc = idx & 31;
    dst[(size_t)(nb + nr) * 1024 + kb + kc] = t[nr][kc];
  }
}

// ---------------- standalone RoPE + head-scatter (f64 trig) ----------------
__global__ __launch_bounds__(256) void k_rope(const float* __restrict__ lin,
                                              __hip_bfloat16* __restrict__ outp,
                                              const int* __restrict__ kidx,
                                              int sh, int qoff) {
  int gid = blockIdx.x * 256 + threadIdx.x;
  int row = gid >> 9, j = gid & 511;
  int b = row >> sh, s = row & ((1 << sh) - 1);
  int idx = kidx[b * 1024 + qoff + s];
  float2 v = ((const float2*)lin)[(size_t)row * 512 + j];
  double inv = pow(10000.0, -(double)j / 512.0);
  double ds, dc;
  sincos((double)idx * inv, &ds, &dc);
  float c = (float)dc, sn = (float)ds;
  float e0 = v.x * c - v.y * sn;
  float e1 = v.x * sn + v.y * c;
  int h = j >> 5, d0 = (2 * j) & 63;
  size_t o = ((size_t)(b * 16 + h) * ((size_t)1 << sh) + s) * 64 + d0;
  unsigned u = ((unsigned)(unsigned short)f2bs(e1) << 16) |
               (unsigned)(unsigned short)f2bs(e0);
  *(unsigned*)((short*)outp + o) = u;
}

// ---------------- generic 128x128 MFMA GEMM (m97 structure) ----------------
enum { CM_BF16 = 0, CM_F32 = 2, CM_F32ACC = 3, CM_VT = 4 };

__global__ __launch_bounds__(256) void k_gemm(
    const short* __restrict__ A, const short* __restrict__ Bt,
    const float* __restrict__ bias, int amode, int cmode,
    void* __restrict__ Cout) {
  __shared__ __align__(16) short lA[128 * 32];
  __shared__ __align__(16) short lB[128 * 32];
  const int tid = threadIdx.x;
  const int lane = tid & 63;
  const int wv = tid >> 6;
  const int wm = wv >> 1, wn = wv & 1;
  const int lo = lane & 15, hi = lane >> 4;
  const int tm0 = blockIdx.x * 128;
  const int tn0 = blockIdx.y * 128;

  const f32x4 vz = {0.f, 0.f, 0.f, 0.f};
  f32x4 acc[4][4];
#pragma unroll
  for (int m = 0; m < 4; ++m)
#pragma unroll
    for (int n = 0; n < 4; ++n) acc[m][n] = vz;

  for (int kt = 0; kt < 32; ++kt) {
    const int k0 = kt * 32;
    __syncthreads();
#pragma unroll
    for (int i = 0; i < 2; ++i) {
      int f = i * 256 + tid;
      int r = f >> 2;
      int cb = (f & 3) * 16;
      int arow = tm0 + r;
      if (amode) arow = ((arow >> 9) << 10) + 512 + (arow & 511);
      const char* ga = (const char*)(A + (size_t)arow * 1024 + k0) + cb;
      __builtin_amdgcn_global_load_lds(
          (const __attribute__((address_space(1))) void*)ga,
          (__attribute__((address_space(3))) void*)((char*)lA + (size_t)(i * 256 + wv * 64) * 16),
          16, 0, 0);
      int brow = tn0 + r;
      const char* gb = (const char*)(Bt + (size_t)brow * 1024 + k0) + cb;
      __builtin_amdgcn_global_load_lds(
          (const __attribute__((address_space(1))) void*)gb,
          (__attribute__((address_space(3))) void*)((char*)lB + (size_t)(i * 256 + wv * 64) * 16),
          16, 0, 0);
    }
    __syncthreads();
    bf16x8 af[4], bfr[4];
#pragma unroll
    for (int m = 0; m < 4; ++m)
      af[m] = *(const bf16x8*)&lA[(wm * 64 + m * 16 + lo) * 32 + hi * 8];
#pragma unroll
    for (int n = 0; n < 4; ++n)
      bfr[n] = *(const bf16x8*)&lB[(wn * 64 + n * 16 + lo) * 32 + hi * 8];
#pragma unroll
    for (int m = 0; m < 4; ++m)
#pragma unroll
      for (int n = 0; n < 4; ++n)
        acc[m][n] = __builtin_amdgcn_mfma_f32_16x16x32_bf16(af[m], bfr[n], acc[m][n], 0, 0, 0);
  }

  if (cmode == CM_VT) {
    __hip_bfloat16* out = (__hip_bfloat16*)Cout;
#pragma unroll
    for (int m = 0; m < 4; ++m) {
      int row_base = tm0 + wm * 64 + m * 16 + hi * 4;
#pragma unroll
      for (int n = 0; n < 4; ++n) {
        int col = tn0 + wn * 64 + n * 16 + lo;
        float bsv = bias ? bias[col] : 0.f;
        int hh = col >> 6, dd = col & 63;
#pragma unroll
        for (int r = 0; r < 4; ++r) {
          int row = row_base + r;
          int bb = row >> 10, ss = row & 1023;
          out[((size_t)(bb * 16 + hh) * 64 + dd) * 1024 + ss] =
              __float2bfloat16(acc[m][n][r] + bsv);
        }
      }
    }
  } else if (cmode == CM_F32 || cmode == CM_F32ACC) {
    float* out = (float*)Cout;
#pragma unroll
    for (int m = 0; m < 4; ++m) {
      int row_base = tm0 + wm * 64 + m * 16 + hi * 4;
#pragma unroll
      for (int n = 0; n < 4; ++n) {
        int col = tn0 + wn * 64 + n * 16 + lo;
        float bsv = bias ? bias[col] : 0.f;
#pragma unroll
        for (int r = 0; r < 4; ++r) {
          size_t off = (size_t)(row_base + r) * 1024 + col;
          float val = acc[m][n][r] + bsv;
          if (cmode == CM_F32ACC) val += out[off];
          out[off] = val;
        }
      }
    }
  } else {
    __hip_bfloat16* out = (__hip_bfloat16*)Cout;
#pragma unroll
    for (int m = 0; m < 4; ++m) {
      int row_base = tm0 + wm * 64 + m * 16 + hi * 4;
#pragma unroll
      for (int n = 0; n < 4; ++n) {
        int col = tn0 + wn * 64 + n * 16 + lo;
        float bsv = bias ? bias[col] : 0.f;
#pragma unroll
        for (int r = 0; r < 4; ++r) {
          size_t off = (size_t)(row_base + r) * 1024 + col;
          out[off] = __float2bfloat16(acc[m][n][r] + bsv);
        }
      }
    }
  }
}

// ---------------- attention v2 ---------------------------------------------
// grid (qt=32, b=16), 256 threads, 16-head loop inside.
// LDS swizzle: element (q,k) of the 16x1024 S/P tile lives at q*1024 + (k^q).
__global__ __launch_bounds__(256) void k_attn(
    const __hip_bfloat16* __restrict__ qh,
    const __hip_bfloat16* __restrict__ kh,
    const __hip_bfloat16* __restrict__ vt,
    const unsigned char* __restrict__ padraw,
    float* __restrict__ mean_out,
    __hip_bfloat16* __restrict__ oat) {
  __shared__ float Sld[16 * 1024];
  const int qt = blockIdx.x, b = blockIdx.y;
  const int tid = threadIdx.x, lane = tid & 63, wv = tid >> 6;
  const int lo = lane & 15, hi = lane >> 4;
  const f32x4 vz = {0.f, 0.f, 0.f, 0.f};

  // pad-mask element-width detect (bool bytes vs int32/f32 words); see r5.
  bool is_byte = false;
#pragma unroll
  for (int j = 1; j < 256; ++j)
    if ((j & 3) && padraw[j] == 1) is_byte = true;
  const int* ipad = (const int*)padraw;

  // per-lane pad bits for this wave's 16 kpos slots (kpos = wv*256+nt*16+lo)
  unsigned pmask = 0;
#pragma unroll
  for (int nt = 0; nt < 16; ++nt) {
    int kpos = wv * 256 + nt * 16 + lo;
    int pk = is_byte ? (int)padraw[b * 1024 + kpos]
                     : (ipad[b * 1024 + kpos] != 0 ? 1 : 0);
    pmask |= (unsigned)(pk != 0) << nt;
  }

  float macc[4][16];
#pragma unroll
  for (int rr = 0; rr < 4; ++rr)
#pragma unroll
    for (int i = 0; i < 16; ++i) macc[rr][i] = 0.f;

  for (int h = 0; h < 16; ++h) {
    const __hip_bfloat16* qbh =
        qh + ((size_t)(b * 16 + h) * 512 + (size_t)qt * 16) * 64;
    const __hip_bfloat16* kbh = kh + (size_t)(b * 16 + h) * 1024 * 64;
    const __hip_bfloat16* vbh = vt + (size_t)(b * 16 + h) * 64 * 1024;

    bf16x8 qf0 = *(const bf16x8*)(qbh + (size_t)lo * 64 + hi * 8);
    bf16x8 qf1 = *(const bf16x8*)(qbh + (size_t)lo * 64 + 32 + hi * 8);

    // ---- S = Q K^T / 8 + mask (wave owns kpos strip [wv*256,+256)) ----
    bf16x8 kf0 = *(const bf16x8*)(kbh + (size_t)(wv * 256 + lo) * 64 + hi * 8);
    bf16x8 kf1 = *(const bf16x8*)(kbh + (size_t)(wv * 256 + lo) * 64 + 32 + hi * 8);
#pragma unroll
    for (int nt = 0; nt < 16; ++nt) {
      bf16x8 nf0 = kf0, nf1 = kf1;
      if (nt < 15) {
        int kr = wv * 256 + (nt + 1) * 16 + lo;
        nf0 = *(const bf16x8*)(kbh + (size_t)kr * 64 + hi * 8);
        nf1 = *(const bf16x8*)(kbh + (size_t)kr * 64 + 32 + hi * 8);
      }
      f32x4 sa = vz;
      sa = __builtin_amdgcn_mfma_f32_16x16x32_bf16(qf0, kf0, sa, 0, 0, 0);
      sa = __builtin_amdgcn_mfma_f32_16x16x32_bf16(qf1, kf1, sa, 0, 0, 0);
      int kpos = wv * 256 + nt * 16 + lo;
      int pk = (pmask >> nt) & 1;
#pragma unroll
      for (int r = 0; r < 4; ++r) {
        int q = hi * 4 + r;
        int qg = 512 + qt * 16 + q;
        float sv = sa[r] * 0.125f;
        bool msk = (kpos > qg) || (kpos < qg && pk != 0);
        Sld[q * 1024 + (kpos ^ q)] = msk ? -1e30f : sv;
      }
      kf0 = nf0; kf1 = nf1;
    }
    __syncthreads();

    // ---- softmax (wave owns rows [wv*4,+4)); mean acc in regs ----
#pragma unroll
    for (int rr = 0; rr < 4; ++rr) {
      int q = wv * 4 + rr;
      float* row = Sld + q * 1024;
      float v[16], mx = -1e30f;
#pragma unroll
      for (int i = 0; i < 16; ++i) {
        v[i] = row[(lane + i * 64) ^ q];
        mx = fmaxf(mx, v[i]);
      }
#pragma unroll
      for (int off = 32; off > 0; off >>= 1) mx = fmaxf(mx, __shfl_xor(mx, off));
      float sum = 0.f;
#pragma unroll
      for (int i = 0; i < 16; ++i) { v[i] = __expf(v[i] - mx); sum += v[i]; }
#pragma unroll
      for (int off = 32; off > 0; off >>= 1) sum += __shfl_xor(sum, off);
      float invs = 1.0f / sum;
#pragma unroll
      for (int i = 0; i < 16; ++i) {
        float p = v[i] * invs;
        row[(lane + i * 64) ^ q] = p;
        macc[rr][i] += p;
      }
    }
    __syncthreads();

    // ---- O = P V (wave owns d cols [wv*16,+16)); swizzled b32 P reads ----
    f32x4 oacc = vz;
    bf16x8 vf = *(const bf16x8*)(vbh + (size_t)(wv * 16 + lo) * 1024 + hi * 8);
    const float* prow = Sld + lo * 1024;
#pragma unroll
    for (int kc = 0; kc < 32; ++kc) {
      bf16x8 nvf = vf;
      if (kc < 31)
        nvf = *(const bf16x8*)(vbh + (size_t)(wv * 16 + lo) * 1024 +
                               (kc + 1) * 32 + hi * 8);
      int kb = kc * 32 + hi * 8;
      bf16x8 pa;
#pragma unroll
      for (int j = 0; j < 8; ++j) pa[j] = f2bs(prow[(kb + j) ^ lo]);
      oacc = __builtin_amdgcn_mfma_f32_16x16x32_bf16(pa, vf, oacc, 0, 0, 0);
      vf = nvf;
    }
#pragma unroll
    for (int r = 0; r < 4; ++r) {
      int q = qt * 16 + hi * 4 + r;
      oat[((size_t)b * 512 + q) * 1024 + h * 64 + wv * 16 + lo] =
          __float2bfloat16(oacc[r]);
    }
    __syncthreads();
  }

  // ---- head-mean store (replaces atomics; covers out1 fully) ----
#pragma unroll
  for (int rr = 0; rr < 4; ++rr) {
    size_t mrow = ((size_t)b * 512 + (size_t)qt * 16 + wv * 4 + rr) * 1024;
#pragma unroll
    for (int i = 0; i < 16; ++i)
      mean_out[mrow + lane + i * 64] = macc[rr][i] * 0.0625f;
  }
}

// ---------------- gate elementwise kernels (f32 pre-activations) -----------
__global__ __launch_bounds__(256) void k_rx(const float* __restrict__ Rb,
                                            const float* __restrict__ x,
                                            short* __restrict__ rx) {
  size_t base = ((size_t)blockIdx.x * 256 + threadIdx.x) * 4;
  int row = (int)(base >> 10), col = (int)(base & 1023);
  int b = row >> 9, s = row & 511;
  const float* xp = x + ((size_t)(b * 1024 + 512 + s) << 10) + col;
  f32x4 rv = *(const f32x4*)(Rb + base);
  f32x4 xv = *(const f32x4*)xp;
  typedef __attribute__((ext_vector_type(4))) short s16x4;
  s16x4 o;
#pragma unroll
  for (int j = 0; j < 4; ++j) {
    float r = 1.f / (1.f + __expf(-rv[j]));
    o[j] = f2bs(r * xv[j]);
  }
  *(s16x4*)(rx + base) = o;
}

__global__ __launch_bounds__(256) void k_final(const float* __restrict__ Zb,
                                               const float* __restrict__ Hb,
                                               const float* __restrict__ x,
                                               float* __restrict__ out0) {
  size_t base = ((size_t)blockIdx.x * 256 + threadIdx.x) * 4;
  int row = (int)(base >> 10), col = (int)(base & 1023);
  int b = row >> 9, s = row & 511;
  const float* xp = x + ((size_t)(b * 1024 + 512 + s) << 10) + col;
  f32x4 zv = *(const f32x4*)(Zb + base);
  f32x4 hv = *(const f32x4*)(Hb + base);
  f32x4 xv = *(const f32x4*)xp;
  f32x4 o;
#pragma unroll
  for (int j = 0; j < 4; ++j) {
    float z = 1.f / (1.f + __expf(-zv[j]));
    float hh = tanhf(hv[j]);
    o[j] = (1.f - z) * xv[j] + z * hh;
  }
  *(f32x4*)(out0 + base) = o;
}

// ============================================================================
extern "C" void kernel_launch(void* const* d_in, const int* in_sizes, int n_in,
                              void* d_out, int out_size, void* d_ws, size_t ws_size,
                              hipStream_t stream) {
  const float* key_in = (const float*)d_in[0];
  const int* key_index = (const int*)d_in[1];
  const unsigned char* pad = (const unsigned char*)d_in[2];
  const float* W[10] = {(const float*)d_in[3],  (const float*)d_in[5],
                        (const float*)d_in[7],  (const float*)d_in[9],
                        (const float*)d_in[11], (const float*)d_in[13],
                        (const float*)d_in[15], (const float*)d_in[17],
                        (const float*)d_in[19], (const float*)d_in[21]};
  const float* bq  = (const float*)d_in[4];
  const float* bk  = (const float*)d_in[6];
  const float* bv  = (const float*)d_in[8];
  const float* bo  = (const float*)d_in[10];
  const float* bxr = (const float*)d_in[12];
  const float* byr = (const float*)d_in[14];
  const float* bxz = (const float*)d_in[16];
  const float* byz = (const float*)d_in[18];
  const float* bxg = (const float*)d_in[20];
  const float* byg = (const float*)d_in[22];

  char* ws = (char*)d_ws;
  short* wt = (short*)(ws + OFF_WT);
  short* xbf = (short*)(ws + OFF_XBF);
  __hip_bfloat16* qh = (__hip_bfloat16*)(ws + OFF_QH);
  __hip_bfloat16* kh = (__hip_bfloat16*)(ws + OFF_KH);
  __hip_bfloat16* vt = (__hip_bfloat16*)(ws + OFF_VT);
  float* qlin = (float*)(ws + OFF_QLIN);
  float* klin = (float*)(ws + OFF_KLIN);
  float* Rb = (float*)(ws + OFF_RB);
  float* Zb = (float*)(ws + OFF_ZB);
  __hip_bfloat16* oat = (__hip_bfloat16*)(ws + OFF_OAT);
  short* o2 = (short*)(ws + OFF_O2);
  short* rx = (short*)(ws + OFF_RX);
  float* Hb = (float*)(ws + OFF_HB);

  float* out0 = (float*)d_out;
  float* out1 = out0 + (size_t)8388608;

  W10 wargs;
  for (int i = 0; i < 10; ++i) wargs.p[i] = W[i];
  k_cvtx<<<8192, 256, 0, stream>>>(key_in, xbf);
  k_wt<<<dim3(32, 32, 10), 256, 0, stream>>>(wargs, wt);

  // q/k/v projections (+rope, +fused V-transpose)
  k_gemm<<<dim3(64, 8), 256, 0, stream>>>(xbf, wt + (size_t)0 * 1048576, bq, 1, CM_F32,
                                          (void*)qlin);
  k_rope<<<16384, 256, 0, stream>>>(qlin, qh, key_index, 9, 512);
  k_gemm<<<dim3(128, 8), 256, 0, stream>>>(xbf, wt + (size_t)1 * 1048576, bk, 0, CM_F32,
                                           (void*)klin);
  k_rope<<<32768, 256, 0, stream>>>(klin, kh, key_index, 10, 0);
  k_gemm<<<dim3(128, 8), 256, 0, stream>>>(xbf, wt + (size_t)2 * 1048576, bv, 0, CM_VT,
                                           (void*)vt);

  // attention (head loop inside; mean written directly, no atomics)
  k_attn<<<dim3(32, 16), 256, 0, stream>>>(qh, kh, vt, pad, out1, oat);

  // output projection + gates
  k_gemm<<<dim3(64, 8), 256, 0, stream>>>((const short*)oat, wt + (size_t)3 * 1048576, bo,
                                          0, CM_BF16, (void*)o2);
  k_gemm<<<dim3(64, 8), 256, 0, stream>>>(xbf, wt + (size_t)4 * 1048576, bxr, 1, CM_F32,
                                          (void*)Rb);
  k_gemm<<<dim3(64, 8), 256, 0, stream>>>(o2, wt + (size_t)5 * 1048576, byr, 0, CM_F32ACC,
                                          (void*)Rb);
  k_gemm<<<dim3(64, 8), 256, 0, stream>>>(xbf, wt + (size_t)6 * 1048576, bxz, 1, CM_F32,
                                          (void*)Zb);
  k_gemm<<<dim3(64, 8), 256, 0, stream>>>(o2, wt + (size_t)7 * 1048576, byz, 0, CM_F32ACC,
                                          (void*)Zb);
  k_rx<<<8192, 256, 0, stream>>>(Rb, key_in, rx);
  k_gemm<<<dim3(64, 8), 256, 0, stream>>>(rx, wt + (size_t)8 * 1048576, bxg, 0, CM_F32,
                                          (void*)Hb);
  k_gemm<<<dim3(64, 8), 256, 0, stream>>>(o2, wt + (size_t)9 * 1048576, byg, 0, CM_F32ACC,
                                          (void*)Hb);
  k_final<<<8192, 256, 0, stream>>>(Zb, Hb, key_in, out0);
}